// Round 17
// baseline (17971.658 us; speedup 1.0000x reference)
//
#include <hip/hip_runtime.h>
#include <hip/hip_bf16.h>

#define Bv 64
#define Tv 512
#define Iv 1024
#define Hv 1024
#define G4v 4096
#define BH (Bv * Hv)
#define NHB 64          // h-blocks (the ONLY blocks now; x-GEMM fused in)
#define FSTR 16         // flag padding: 64B

typedef __attribute__((ext_vector_type(8))) short bf16x8;
typedef __attribute__((ext_vector_type(4))) float f32x4;

#define LOADC(p)    __hip_atomic_load((p), __ATOMIC_RELAXED, __HIP_MEMORY_SCOPE_AGENT)
#define STOREC(p,v) __hip_atomic_store((p), (v), __ATOMIC_RELAXED, __HIP_MEMORY_SCOPE_AGENT)

__device__ __forceinline__ float sigmoid_f(float v) { return 1.f / (1.f + __expf(-v)); }
__device__ __forceinline__ float tanh_f(float v) { return 1.f - 2.f / (__expf(2.f * v) + 1.f); }

// 2-byte agent-visible (sc1 write-through) store: publish bf16 h cells.
__device__ __forceinline__ void store_short_sc1(void* p, unsigned short v) {
  asm volatile("global_store_short %0, %1, off sc1" :: "v"(p), "v"((unsigned)v) : "memory");
}

// ---------------- prep: weights -> bf16, bias sum, zero h slots 0-1 + flags ----------------
__global__ void prep(const float* __restrict__ w_ih, const float* __restrict__ w_hh,
                     const float* __restrict__ b_ih, const float* __restrict__ b_hh,
                     __hip_bfloat16* __restrict__ wbih, __hip_bfloat16* __restrict__ wbhh,
                     float* __restrict__ bias, __hip_bfloat16* __restrict__ hbuf,
                     unsigned* __restrict__ hflag) {
  unsigned i = blockIdx.x * 256u + threadIdx.x;   // grid covers exactly 4096*1024
  wbih[i] = __float2bfloat16(w_ih[i]);
  wbhh[i] = __float2bfloat16(w_hh[i]);
  if (i < (unsigned)G4v) bias[i] = b_ih[i] + b_hh[i];
  if (i < 2u * BH) hbuf[i] = __float2bfloat16(0.f);   // ring slots 0-1 / pingpong both
  if (i < (unsigned)(NHB * FSTR)) hflag[i] = 0u;
}

// ---------------- persistent fused LSTM: 64 blocks, x-GEMM in the sync-wait shadow ----------------
// Each block owns 64 gate-cols (= 16 h-cols x 4 gates). W_hh slice in LDS (128KB).
// Per step t: poll flags>=t -> A-burst (ring cached reads) -> h-MFMA -> gates DIRECTLY
// on fragments (R12: thread owns rows wave*16+lkg*4+{0..3}, col wg*16+lrow; nf=gate) ->
// publish h (sc1) -> drain -> flag -> out stores -> compute acc_x(t+2) via x-GEMM with
// W_ih read from GLOBAL (L2-resident slice) -- this fills the window where the block
// would otherwise spin waiting for other blocks' flags. acc_x double-buffered (A=even t,
// B=odd t) with STATIC names (rule #20) via 2-step-unrolled loop. No producers, no xg
// ring, no xflag: two LLC legs and 128 blocks of contention removed vs R16.
__global__ void __launch_bounds__(256, 1) lstm_main(
    const float* __restrict__ x,
    const __hip_bfloat16* __restrict__ wbih,   // read from global during x-GEMM
    const __hip_bfloat16* __restrict__ wbhh,
    const float* __restrict__ bias,
    __hip_bfloat16* __restrict__ hbuf,   // ring [Tv+1][B][H] or pingpong [2][B][H]
    float* __restrict__ out,             // B*T*H + B*H + B*H
    unsigned* __restrict__ hflag,
    int ring)
{
  extern __shared__ char lds[];

  const int tid  = threadIdx.x;
  const int lane = tid & 63;
  const int wave = tid >> 6;
  const int lrow = lane & 15;        // A row / B,D col within fragment
  const int lkg  = lane >> 4;        // 0..3
  const int lk   = lkg * 8;          // k offset within 32
  const int wg   = blockIdx.x;       // gate-col slice 0..63

  // ---- stage this block's 64x1024 W_hh slice into LDS (once, swizzled) ----
  {
    for (int c = tid; c < 8192; c += 256) {       // 8192 chunks of 16B = 128KB
      int n   = c >> 7;
      int k16 = c & 127;
      int gc  = ((n >> 4) << 10) + (wg << 4) + (n & 15);
      uint4 v = *(const uint4*)(wbhh + ((size_t)gc << 10) + (k16 << 3));
      unsigned byt = (unsigned)((n << 11) + (k16 << 4)) ^ ((unsigned)(n & 7) << 4);
      *(uint4*)(&lds[byt]) = v;
    }
  }
  __syncthreads();

  const int orow0 = wave * 16 + (lkg << 2);  // first owned batch row (C/D frag)
  const int ocol  = (wg << 4) + lrow;        // owned h column (global)
  const int ar    = wave * 16 + lrow;        // A row this lane loads
  float c_state[4] = {0.f, 0.f, 0.f, 0.f};
  float biasv[4];
  #pragma unroll
  for (int g = 0; g < 4; ++g) biasv[g] = bias[(g << 10) + ocol];

  // ---- x-GEMM: acc_x(tx) = x_tx @ W_ih_slice^T, fragment layout == h-GEMM's ----
  // A: x rows wave*16+lrow (f32->bf16 in-reg). B: W_ih from GLOBAL (16B/lane/chunk;
  // slice is L2-resident after first step). ~128 MFMA/wave, runs in sync shadow.
  auto xgemm = [&](int tx, f32x4 (&accx)[4]) {
    #pragma unroll
    for (int nf = 0; nf < 4; ++nf) accx[nf] = f32x4{0.f, 0.f, 0.f, 0.f};
    const float* xt = x + (size_t)ar * (Tv * Iv) + (size_t)tx * Iv + lk;
    #pragma unroll 4
    for (int ks = 0; ks < 32; ++ks) {
      float4 f0 = *(const float4*)(xt + (ks << 5));
      float4 f1 = *(const float4*)(xt + (ks << 5) + 4);
      union { __hip_bfloat16 e[8]; bf16x8 v; } u;
      u.e[0] = __float2bfloat16(f0.x); u.e[1] = __float2bfloat16(f0.y);
      u.e[2] = __float2bfloat16(f0.z); u.e[3] = __float2bfloat16(f0.w);
      u.e[4] = __float2bfloat16(f1.x); u.e[5] = __float2bfloat16(f1.y);
      u.e[6] = __float2bfloat16(f1.z); u.e[7] = __float2bfloat16(f1.w);
      #pragma unroll
      for (int nf = 0; nf < 4; ++nf) {
        int gc = (nf << 10) + (wg << 4) + lrow;
        bf16x8 b = *(const bf16x8*)(wbih + (size_t)gc * 1024 + (ks << 5) + lk);
        accx[nf] = __builtin_amdgcn_mfma_f32_16x16x32_bf16(u.v, b, accx[nf], 0, 0, 0);
      }
    }
  };

  // ---- one recurrence step; accx is the pre-computed x contribution for step t.
  // At the end (in the sync shadow) recomputes accx for step t+2.
  auto step_body = [&](int t, f32x4 (&accx)[4]) {
    // poll (wave 0): all blocks published h_t (flag >= t)
    if (wave == 0) {
      const unsigned ht = (unsigned)t;
      for (;;) {
        unsigned hf = LOADC(&hflag[lane * FSTR]);
        if (__all(hf >= ht)) break;
        __builtin_amdgcn_s_sleep(1);
      }
    }
    __syncthreads();
    asm volatile("" ::: "memory");
    // A burst + h-MFMA
    f32x4 acc[4];
    #pragma unroll
    for (int nf = 0; nf < 4; ++nf) acc[nf] = f32x4{0.f, 0.f, 0.f, 0.f};
    bf16x8 aqv[32];
    if (ring) {
      const char* hrow = (const char*)(hbuf + (size_t)t * BH) + ((size_t)ar << 11) + (lkg << 4);
      #pragma unroll
      for (int ks = 0; ks < 32; ++ks)
        aqv[ks] = *(const bf16x8*)(hrow + (ks << 6));
    } else {
      const unsigned long long* hq =
          (const unsigned long long*)(hbuf + (size_t)(t & 1) * BH) + (size_t)ar * 256 + lkg * 2;
      #pragma unroll
      for (int ks = 0; ks < 32; ++ks) {
        union { unsigned long long q[2]; bf16x8 v; } ua;
        ua.q[0] = LOADC(hq + ks * 8);
        ua.q[1] = LOADC(hq + ks * 8 + 1);
        aqv[ks] = ua.v;
      }
    }
    #pragma unroll
    for (int ks = 0; ks < 32; ++ks) {
      int k0 = (ks << 5) + lk;
      #pragma unroll
      for (int nf = 0; nf < 4; ++nf) {
        int n = nf * 16 + lrow;
        unsigned byt = (unsigned)((n << 11) + (k0 << 1)) ^ ((unsigned)(n & 7) << 4);
        bf16x8 b = *(const bf16x8*)(&lds[byt]);
        acc[nf] = __builtin_amdgcn_mfma_f32_16x16x32_bf16(aqv[ks], b, acc[nf], 0, 0, 0);
      }
    }
    // gates directly on fragments: cells (orow0+r, ocol); nf = gate index
    float hv[4];
    #pragma unroll
    for (int r = 0; r < 4; ++r) {
      float g0 = (acc[0][r] + accx[0][r]) + biasv[0];
      float g1 = (acc[1][r] + accx[1][r]) + biasv[1];
      float g2 = (acc[2][r] + accx[2][r]) + biasv[2];
      float g3 = (acc[3][r] + accx[3][r]) + biasv[3];
      float ig = sigmoid_f(g0);
      float fg = sigmoid_f(g1);
      float gg = tanh_f(g2);
      float og = sigmoid_f(g3);
      float cv = fg * c_state[r] + ig * gg;
      c_state[r] = cv;
      hv[r] = og * tanh_f(cv);
    }
    // publish h (4x2B sc1) -> drain -> barrier -> flag
    {
      __hip_bfloat16* hs = hbuf
          + (ring ? (size_t)(t + 1) * BH : (size_t)((t + 1) & 1) * BH) + ocol;
      #pragma unroll
      for (int r = 0; r < 4; ++r) {
        __hip_bfloat16 hb = __float2bfloat16(hv[r]);
        store_short_sc1(hs + ((size_t)(orow0 + r) << 10), *(unsigned short*)&hb);
      }
    }
    asm volatile("s_waitcnt vmcnt(0)" ::: "memory");
    __syncthreads();                    // all waves' h stores at LLC
    if (tid == 0) STOREC(&hflag[wg * FSTR], (unsigned)(t + 1));
    // out stores after the flag: off the critical path
    #pragma unroll
    for (int r = 0; r < 4; ++r) {
      float* ow = out + (size_t)(orow0 + r) * (Tv * Hv) + ((size_t)t << 10) + ocol;
      __builtin_nontemporal_store(hv[r], ow);
    }
    if (t == Tv - 1) {
      #pragma unroll
      for (int r = 0; r < 4; ++r) {
        float* hn = out + (size_t)Bv * Tv * Hv + ((size_t)(orow0 + r) << 10) + ocol;
        __builtin_nontemporal_store(hv[r], hn);
        __builtin_nontemporal_store(c_state[r], hn + BH);
      }
    }
    // sync shadow: compute x contribution for step t+2 while other blocks'
    // flags propagate. By the next poll this block needs, they've landed.
    if (t + 2 < Tv) xgemm(t + 2, accx);
  };

  // ---- prologue: x contributions for steps 0 and 1; h_0 = 0 from prep ----
  f32x4 accxA[4], accxB[4];
  xgemm(0, accxA);
  xgemm(1, accxB);

  for (int t = 0; t < Tv; t += 2) {
    step_body(t,     accxA);
    step_body(t + 1, accxB);
  }
}

// ---------------- host launch ----------------
extern "C" void kernel_launch(void* const* d_in, const int* in_sizes, int n_in,
                              void* d_out, int out_size, void* d_ws, size_t ws_size,
                              hipStream_t stream) {
  const float* x    = (const float*)d_in[0];
  const float* w_ih = (const float*)d_in[1];
  const float* b_ih = (const float*)d_in[2];
  const float* w_hh = (const float*)d_in[3];
  const float* b_hh = (const float*)d_in[4];
  float* out = (float*)d_out;

  char* ws = (char*)d_ws;
  __hip_bfloat16* wbih = (__hip_bfloat16*)(ws);                        // 8 MB
  __hip_bfloat16* wbhh = (__hip_bfloat16*)(ws + ((size_t)8 << 20));    // 8 MB
  float*          bias = (float*)(ws + ((size_t)16 << 20));            // 16 KB
  unsigned*       hflag= (unsigned*)(ws + ((size_t)26 << 20));         // 4 KB

  // ring mode: hbuf = [Tv+1][B][H] bf16 at 32MB (needs ~99.2MB total ws)
  const size_t ringBytes = (size_t)(Tv + 1) * BH * 2;
  const size_t needRing  = ((size_t)32 << 20) + ringBytes;
  const int ring = (ws_size >= needRing) ? 1 : 0;
  __hip_bfloat16* hbuf = ring
      ? (__hip_bfloat16*)(ws + ((size_t)32 << 20))
      : (__hip_bfloat16*)(ws + ((size_t)16 << 20) + 65536);

  hipLaunchKernelGGL(prep, dim3(16384), dim3(256), 0, stream,
                     w_ih, w_hh, b_ih, b_hh, wbih, wbhh, bias, hbuf, hflag);

  const unsigned ldsBytes = 131072u;   // W_hh slice only (no gbuf: fragment gates)
  hipFuncSetAttribute((const void*)lstm_main,
                      hipFuncAttributeMaxDynamicSharedMemorySize, (int)ldsBytes);

  const float* xA = x;
  const __hip_bfloat16* wbihA = wbih;
  const __hip_bfloat16* wbhhA = wbhh;
  const float* biasA = bias;
  __hip_bfloat16* hbufA = hbuf;
  float* outA = out;
  unsigned* hflagA = hflag;
  int ringA = ring;
  void* args[8] = {(void*)&xA, (void*)&wbihA, (void*)&wbhhA, (void*)&biasA,
                   (void*)&hbufA, (void*)&outA, (void*)&hflagA, (void*)&ringA};

  // Coop launch can reject silently (R5/R6). Our sync is flag-based only and
  // 131072B LDS forces 1 block/CU; 64 blocks trivially co-reside. Fall back.
  hipError_t lerr = hipLaunchCooperativeKernel((const void*)lstm_main, dim3(NHB),
                                               dim3(256), args, ldsBytes, stream);
  if (lerr != hipSuccess) {
    (void)hipGetLastError();
    hipLaunchKernelGGL(lstm_main, dim3(NHB), dim3(256), ldsBytes, stream,
                       xA, wbihA, wbhhA, biasA, hbufA, outA, hflagA, ringA);
  }
}

// Round 18
// 4570.547 us; speedup vs baseline: 3.9321x; 3.9321x over previous
//
#include <hip/hip_runtime.h>
#include <hip/hip_bf16.h>

#define Bv 64
#define Tv 512
#define Iv 1024
#define Hv 1024
#define G4v 4096
#define BH (Bv * Hv)
#define NHB 64          // recurrent blocks
#define NXB 128         // producer blocks (2 per 64-col slice, row-split)
#define NBLK (NHB + NXB)
#define DEPTH 8         // xg ring depth (power of 2)
#define FSTR 16         // flag padding: 64B

typedef __attribute__((ext_vector_type(8))) short bf16x8;
typedef __attribute__((ext_vector_type(4))) float f32x4;

#define LOADC(p)    __hip_atomic_load((p), __ATOMIC_RELAXED, __HIP_MEMORY_SCOPE_AGENT)
#define STOREC(p,v) __hip_atomic_store((p), (v), __ATOMIC_RELAXED, __HIP_MEMORY_SCOPE_AGENT)

__device__ __forceinline__ float sigmoid_f(float v) { return 1.f / (1.f + __expf(-v)); }
__device__ __forceinline__ float tanh_f(float v) { return 1.f - 2.f / (__expf(2.f * v) + 1.f); }

// ---------------- prep: weights -> bf16, bias sum, zero h slots 0-1 + flags ----------------
__global__ void prep(const float* __restrict__ w_ih, const float* __restrict__ w_hh,
                     const float* __restrict__ b_ih, const float* __restrict__ b_hh,
                     __hip_bfloat16* __restrict__ wbih, __hip_bfloat16* __restrict__ wbhh,
                     float* __restrict__ bias, __hip_bfloat16* __restrict__ hbuf,
                     unsigned* __restrict__ hflag, unsigned* __restrict__ xflag) {
  unsigned i = blockIdx.x * 256u + threadIdx.x;   // grid covers exactly 4096*1024
  wbih[i] = __float2bfloat16(w_ih[i]);
  wbhh[i] = __float2bfloat16(w_hh[i]);
  if (i < (unsigned)G4v) bias[i] = b_ih[i] + b_hh[i];
  if (i < 2u * BH) hbuf[i] = __float2bfloat16(0.f);   // ring slots 0-1 / pingpong both
  if (i < (unsigned)(NHB * FSTR)) hflag[i] = 0u;
  if (i < (unsigned)(NXB * FSTR)) xflag[i] = 0u;
}

// ---------------- persistent dataflow LSTM (R16 structure; best measured: 4584us) ----------------
// blocks 0..63: h-blocks; blocks 64..191: x-producer blocks.
// RING MODE: hbuf is a [Tv+1][B][H] bf16 ring. Step t READS slot t with NORMAL
// CACHED loads (virgin address each step -> staleness impossible; 8 blocks/XCD
// share the lines in L2) and WRITES slot t+1 with sc1 write-through.
// A-loads are a single 32x16B burst -> ONE exposed LLC round trip.
// No trailing __syncthreads (provably redundant: gbuf reads of step t precede
// t's pre-flag barrier; gbuf writes of t+1 happen after t+1's post-poll barrier).
__global__ void __launch_bounds__(256, 1) lstm_main(
    const float* __restrict__ x,
    const __hip_bfloat16* __restrict__ wbih,
    const __hip_bfloat16* __restrict__ wbhh,
    const float* __restrict__ bias,
    __hip_bfloat16* __restrict__ hbuf,   // ring [Tv+1][B][H] or pingpong [2][B][H]
    float* __restrict__ xg,              // [DEPTH][B][4H] f32 ring (sc1)
    float* __restrict__ out,             // B*T*H + B*H + B*H
    unsigned* __restrict__ hflag,
    unsigned* __restrict__ xflag,
    int ring)
{
  extern __shared__ char lds[];
  float* gbuf = (float*)(lds + 131072);

  const int bid  = blockIdx.x;
  const bool is_h = (bid < NHB);
  const int tid  = threadIdx.x;
  const int lane = tid & 63;
  const int wave = tid >> 6;
  const int lrow = lane & 15;        // A row / B,D col within fragment
  const int lkg  = lane >> 4;        // 0..3
  const int lk   = lkg * 8;          // k offset within 32

  const int wg = is_h ? bid : ((bid - NHB) >> 1);   // gate-col slice 0..63
  const int rh = is_h ? 0 : ((bid - NHB) & 1);      // x row-half

  // ---- stage this block's 64x1024 weight slice into LDS (once, swizzled) ----
  {
    const __hip_bfloat16* wsrc = is_h ? wbhh : wbih;
    for (int c = tid; c < 8192; c += 256) {
      int n   = c >> 7;
      int k16 = c & 127;
      int gc  = ((n >> 4) << 10) + (wg << 4) + (n & 15);
      uint4 v = *(const uint4*)(wsrc + ((size_t)gc << 10) + (k16 << 3));
      unsigned byt = (unsigned)((n << 11) + (k16 << 4)) ^ ((unsigned)(n & 7) << 4);
      *(uint4*)(&lds[byt]) = v;
    }
  }
  __syncthreads();

  if (!is_h) {
    // ================= x-producer block =================
    const int j  = bid - NHB;
    const int wr = wave & 1;
    const int wc = wave >> 1;
    const int arow = rh * 32 + wr * 16 + lrow;
    const float* xa = x + (size_t)arow * (Tv * Iv) + lk;

    for (int t = 0; t < Tv; ++t) {
      if (t >= DEPTH) {
        if (wave == 0) {
          const unsigned tgt = (unsigned)(t - DEPTH + 1);
          for (;;) {
            unsigned hf = LOADC(&hflag[lane * FSTR]);
            if (__all(hf >= tgt)) break;
            __builtin_amdgcn_s_sleep(4);
          }
        }
        __syncthreads();
        asm volatile("" ::: "memory");
      }
      f32x4 acc[2];
      acc[0] = f32x4{0.f,0.f,0.f,0.f}; acc[1] = f32x4{0.f,0.f,0.f,0.f};
      const float* xt = xa + (size_t)t * Iv;
      #pragma unroll 4
      for (int ks = 0; ks < 32; ++ks) {
        int k0 = (ks << 5) + lk;
        float4 f0 = *(const float4*)(xt + (ks << 5));
        float4 f1 = *(const float4*)(xt + (ks << 5) + 4);
        union { __hip_bfloat16 e[8]; bf16x8 v; } u;
        u.e[0] = __float2bfloat16(f0.x); u.e[1] = __float2bfloat16(f0.y);
        u.e[2] = __float2bfloat16(f0.z); u.e[3] = __float2bfloat16(f0.w);
        u.e[4] = __float2bfloat16(f1.x); u.e[5] = __float2bfloat16(f1.y);
        u.e[6] = __float2bfloat16(f1.z); u.e[7] = __float2bfloat16(f1.w);
        bf16x8 b0, b1;
        {
          int n = wc * 32 + lrow;
          unsigned byt = (unsigned)((n << 11) + (k0 << 1)) ^ ((unsigned)(n & 7) << 4);
          b0 = *(const bf16x8*)(&lds[byt]);
          n += 16;
          byt = (unsigned)((n << 11) + (k0 << 1)) ^ ((unsigned)(n & 7) << 4);
          b1 = *(const bf16x8*)(&lds[byt]);
        }
        acc[0] = __builtin_amdgcn_mfma_f32_16x16x32_bf16(u.v, b0, acc[0], 0, 0, 0);
        acc[1] = __builtin_amdgcn_mfma_f32_16x16x32_bf16(u.v, b1, acc[1], 0, 0, 0);
      }
      float* dst = xg + (size_t)(t & (DEPTH - 1)) * (Bv * G4v);
      for (int nf = 0; nf < 2; ++nf) {
        int gc  = (wc * 2 + nf) * 1024 + (wg << 4) + lrow;
        int row = rh * 32 + wr * 16 + (lkg << 2);
        for (int r = 0; r < 4; ++r)
          STOREC(&dst[(size_t)(row + r) * G4v + gc], acc[nf][r]);
      }
      asm volatile("s_waitcnt vmcnt(0)" ::: "memory");
      __syncthreads();
      if (tid == 0) STOREC(&xflag[j * FSTR], (unsigned)(t + 1));
      __syncthreads();
    }
    return;
  }

  // ================= h-recurrent block =================
  const int eb  = tid >> 2;
  const int ec0 = (tid & 3) << 2;
  float c_state[4] = {0.f, 0.f, 0.f, 0.f};
  float biasv[16];
  for (int g = 0; g < 4; ++g)
    for (int jj = 0; jj < 4; ++jj)
      biasv[g * 4 + jj] = bias[(g << 10) + (wg << 4) + ec0 + jj];

  const int ar = wave * 16 + lrow;     // A row this lane loads

  for (int t = 0; t < Tv; ++t) {
    // ---- poll (wave 0 only): all h-blocks done t-1; my 2 producers done t ----
    if (wave == 0) {
      const unsigned ht = (unsigned)t, xtg = (unsigned)(t + 1);
      const unsigned* xf = &xflag[(2 * wg + (lane & 1)) * FSTR];
      for (;;) {
        unsigned hf = LOADC(&hflag[lane * FSTR]);
        unsigned xv = LOADC(xf);
        if (__all(hf >= ht && xv >= xtg)) break;
        __builtin_amdgcn_s_sleep(1);
      }
    }
    __syncthreads();
    asm volatile("" ::: "memory");
    // ---- xg slice -> registers (sc1; overlaps the A phase) ----
    float xgv[16];
    {
      const unsigned long long* xq = (const unsigned long long*)
          (xg + (size_t)(t & (DEPTH - 1)) * (Bv * G4v) + (size_t)eb * G4v + (wg << 4) + ec0);
      #pragma unroll
      for (int g = 0; g < 4; ++g) {
        union { unsigned long long q[2]; float f[4]; } ux;
        ux.q[0] = LOADC(xq + g * 512);
        ux.q[1] = LOADC(xq + g * 512 + 1);
        xgv[g * 4 + 0] = ux.f[0]; xgv[g * 4 + 1] = ux.f[1];
        xgv[g * 4 + 2] = ux.f[2]; xgv[g * 4 + 3] = ux.f[3];
      }
    }
    f32x4 acc[4];
    for (int nf = 0; nf < 4; ++nf) acc[nf] = f32x4{0.f,0.f,0.f,0.f};
    if (ring) {
      // ---- RING: normal cached 16B loads from virgin slot t, FULL burst ----
      const __hip_bfloat16* hp2 = hbuf + (size_t)t * BH;
      const char* hrow = (const char*)hp2 + ((size_t)ar << 11) + (lkg << 4);
      bf16x8 aqv[32];
      #pragma unroll
      for (int ks = 0; ks < 32; ++ks)
        aqv[ks] = *(const bf16x8*)(hrow + (ks << 6));
      #pragma unroll
      for (int ks = 0; ks < 32; ++ks) {
        int k0 = (ks << 5) + lk;
        #pragma unroll
        for (int nf = 0; nf < 4; ++nf) {
          int n = nf * 16 + lrow;
          unsigned byt = (unsigned)((n << 11) + (k0 << 1)) ^ ((unsigned)(n & 7) << 4);
          bf16x8 b = *(const bf16x8*)(&lds[byt]);
          acc[nf] = __builtin_amdgcn_mfma_f32_16x16x32_bf16(aqv[ks], b, acc[nf], 0, 0, 0);
        }
      }
    } else {
      // ---- FALLBACK: sc1 pingpong burst ----
      const unsigned long long* hq = (const unsigned long long*)
          (hbuf + (size_t)(t & 1) * BH) + (size_t)ar * 256 + lkg * 2;
      bf16x8 aqv[32];
      #pragma unroll
      for (int ks = 0; ks < 32; ++ks) {
        union { unsigned long long q[2]; bf16x8 v; } ua;
        ua.q[0] = LOADC(hq + ks * 8);
        ua.q[1] = LOADC(hq + ks * 8 + 1);
        aqv[ks] = ua.v;
      }
      #pragma unroll
      for (int ks = 0; ks < 32; ++ks) {
        int k0 = (ks << 5) + lk;
        #pragma unroll
        for (int nf = 0; nf < 4; ++nf) {
          int n = nf * 16 + lrow;
          unsigned byt = (unsigned)((n << 11) + (k0 << 1)) ^ ((unsigned)(n & 7) << 4);
          bf16x8 b = *(const bf16x8*)(&lds[byt]);
          acc[nf] = __builtin_amdgcn_mfma_f32_16x16x32_bf16(aqv[ks], b, acc[nf], 0, 0, 0);
        }
      }
    }
    // ---- exchange gates through LDS ----
    #pragma unroll
    for (int nf = 0; nf < 4; ++nf)
      for (int r = 0; r < 4; ++r)
        gbuf[(wave * 16 + (lkg << 2) + r) * 65 + nf * 16 + lrow] = acc[nf][r];
    __syncthreads();
    float hv[4];
    #pragma unroll
    for (int jj = 0; jj < 4; ++jj) {
      int cc = ec0 + jj;
      float g0 = gbuf[eb * 65 +      cc] + xgv[0 + jj]  + biasv[0 + jj];
      float g1 = gbuf[eb * 65 + 16 + cc] + xgv[4 + jj]  + biasv[4 + jj];
      float g2 = gbuf[eb * 65 + 32 + cc] + xgv[8 + jj]  + biasv[8 + jj];
      float g3 = gbuf[eb * 65 + 48 + cc] + xgv[12 + jj] + biasv[12 + jj];
      float ig = sigmoid_f(g0);
      float fg = sigmoid_f(g1);
      float gg = tanh_f(g2);
      float og = sigmoid_f(g3);
      float cv = fg * c_state[jj] + ig * gg;
      c_state[jj] = cv;
      hv[jj] = og * tanh_f(cv);
    }
    // publish h slice (one 8B sc1 write-through store)
    __hip_bfloat16* hw = hbuf
        + (ring ? (size_t)(t + 1) * BH : (size_t)(t & 1) * BH)
        + ((size_t)eb << 10) + (wg << 4) + ec0;
    union { __hip_bfloat16 h[4]; unsigned long long q; } hu;
    for (int jj = 0; jj < 4; ++jj) hu.h[jj] = __float2bfloat16(hv[jj]);
    STOREC((unsigned long long*)hw, hu.q);
    asm volatile("s_waitcnt vmcnt(0)" ::: "memory");
    __syncthreads();                    // all waves' h stores at LLC (pre-flag barrier)
    if (tid == 0) STOREC(&hflag[wg * FSTR], (unsigned)(t + 1));
    // ---- out stores AFTER flag publish: HBM ack off the critical path ----
    float* ow = out + (size_t)eb * (Tv * Hv) + ((size_t)t << 10) + (wg << 4) + ec0;
    f32x4 ov = {hv[0], hv[1], hv[2], hv[3]};
    __builtin_nontemporal_store(ov, (f32x4*)ow);
    if (t == Tv - 1) {
      float* hn = out + (size_t)Bv * Tv * Hv + ((size_t)eb << 10) + (wg << 4) + ec0;
      float* cn = hn + (size_t)Bv * Hv;
      for (int jj = 0; jj < 4; ++jj) { hn[jj] = hv[jj]; cn[jj] = c_state[jj]; }
    }
    // no trailing __syncthreads — next step's post-poll barrier provides ordering
  }
}

// ---------------- host launch ----------------
extern "C" void kernel_launch(void* const* d_in, const int* in_sizes, int n_in,
                              void* d_out, int out_size, void* d_ws, size_t ws_size,
                              hipStream_t stream) {
  const float* x    = (const float*)d_in[0];
  const float* w_ih = (const float*)d_in[1];
  const float* b_ih = (const float*)d_in[2];
  const float* w_hh = (const float*)d_in[3];
  const float* b_hh = (const float*)d_in[4];
  float* out = (float*)d_out;

  char* ws = (char*)d_ws;
  __hip_bfloat16* wbih = (__hip_bfloat16*)(ws);                        // 8 MB
  __hip_bfloat16* wbhh = (__hip_bfloat16*)(ws + ((size_t)8 << 20));    // 8 MB
  float*          bias = (float*)(ws + ((size_t)16 << 20));            // 16 KB
  float*          xg   = (float*)(ws + ((size_t)18 << 20));            // 8 MB ring
  unsigned*       hflag= (unsigned*)(ws + ((size_t)26 << 20));         // 4 KB
  unsigned*       xflag= (unsigned*)(ws + ((size_t)26 << 20) + 8192);  // 8 KB

  // ring mode: hbuf = [Tv+1][B][H] bf16 at 32MB (needs ~96.1MB total ws)
  const size_t ringBytes = (size_t)(Tv + 1) * BH * 2;
  const size_t needRing  = ((size_t)32 << 20) + ringBytes;
  const int ring = (ws_size >= needRing) ? 1 : 0;
  __hip_bfloat16* hbuf = ring
      ? (__hip_bfloat16*)(ws + ((size_t)32 << 20))
      : (__hip_bfloat16*)(ws + ((size_t)16 << 20) + 65536);

  hipLaunchKernelGGL(prep, dim3(16384), dim3(256), 0, stream,
                     w_ih, w_hh, b_ih, b_hh, wbih, wbhh, bias, hbuf, hflag, xflag);

  const unsigned ldsBytes = 131072u + 64u * 65u * 4u;  // 147712
  hipFuncSetAttribute((const void*)lstm_main,
                      hipFuncAttributeMaxDynamicSharedMemorySize, (int)ldsBytes);

  const float* xA = x;
  const __hip_bfloat16* wbihA = wbih;
  const __hip_bfloat16* wbhhA = wbhh;
  const float* biasA = bias;
  __hip_bfloat16* hbufA = hbuf;
  float* xgA = xg;
  float* outA = out;
  unsigned* hflagA = hflag;
  unsigned* xflagA = xflag;
  int ringA = ring;
  void* args[10] = {(void*)&xA, (void*)&wbihA, (void*)&wbhhA, (void*)&biasA,
                    (void*)&hbufA, (void*)&xgA, (void*)&outA, (void*)&hflagA,
                    (void*)&xflagA, (void*)&ringA};

  // Coop launch can reject silently (R5/R6). Our sync is flag-based only and
  // 147712B LDS forces 1 block/CU -> plain launch co-resides too. Fall back.
  hipError_t lerr = hipLaunchCooperativeKernel((const void*)lstm_main, dim3(NBLK),
                                               dim3(256), args, ldsBytes, stream);
  if (lerr != hipSuccess) {
    (void)hipGetLastError();
    hipLaunchKernelGGL(lstm_main, dim3(NBLK), dim3(256), ldsBytes, stream,
                       xA, wbihA, wbhhA, biasA, hbufA, xgA, outA, hflagA, xflagA, ringA);
  }
}